// Round 1
// 1241.598 us; speedup vs baseline: 1.3638x; 1.3638x over previous
//
#include <hip/hip_runtime.h>

// Grid4D quadrilinear sample, align_corners=True.
// grid: [R=8, X=9, Y=9, U=512, V=512] fp32 (648 MB), xyuv: [N,4] in [0,1]
// out: [N, 8] fp32
//
// R2: bucket-sort points by 16x16 (u,v) tile -> co-resident waves touch a
//     ~1.4 MB line-footprint slab; unique-line floor = 0.68 GB.
// R3 (this round):
//   (a) XCD-affine block remap in gather: physical block p runs on XCD p%8
//       (round-robin dispatch); give each XCD a CONTIGUOUS chunk of the
//       tile-sorted range so each tile slab is fetched by ONE per-XCD L2
//       instead of all 8. Measured R2: FETCH 2.75 GB = 4.2x unique floor.
//   (b) Pad hist/cursor counters to one 64B line each (stride 16 ints):
//       1024 packed ints = 64 L2 lines; ~1.25M device atomics serialized
//       per-line made the scatter/hist pipeline ~905 us of the 1693 total.

#define RR 8
#define SX 9
#define SY 9
#define SU 512
#define SV 512

#define NTU 32          // u tiles (512/16)
#define NTV 32          // v tiles
#define NTILES (NTU * NTV)
#define CPAD 16         // ints per counter slot (64 B) -> one L2 line per counter

__device__ __forceinline__ void split_coord(float p, int size, int& i0, float& f) {
    p = fminf(fmaxf(p, 0.0f), (float)(size - 1));
    float fl = floorf(p);
    int i = (int)fl;
    if (i > size - 2) i = size - 2;   // keep i0+1 in bounds; f hits 1.0 at top edge
    i0 = i;
    f = p - (float)i;
}

__device__ __forceinline__ int tile_of(float4 c, const float* mn, const float* mx) {
    float pu = (c.z - mn[2]) / (mx[2] - mn[2]) * (float)(SU - 1);
    float pv = (c.w - mn[3]) / (mx[3] - mn[3]) * (float)(SV - 1);
    int u0, v0; float fu, fv;
    split_coord(pu, SU, u0, fu);
    split_coord(pv, SV, v0, fv);
    return (u0 >> 4) * NTV + (v0 >> 4);
}

__global__ void zero_kernel(int* p, int n) {
    int i = blockIdx.x * blockDim.x + threadIdx.x;
    if (i < n) p[i] = 0;
}

__global__ __launch_bounds__(256) void hist_kernel(
    const float4* __restrict__ xyuv, const float* __restrict__ mn,
    const float* __restrict__ mx, int* __restrict__ counts, int npts)
{
    __shared__ int h[NTILES];
    for (int i = threadIdx.x; i < NTILES; i += blockDim.x) h[i] = 0;
    __syncthreads();
    int stride = gridDim.x * blockDim.x;
    for (int n = blockIdx.x * blockDim.x + threadIdx.x; n < npts; n += stride)
        atomicAdd(&h[tile_of(xyuv[n], mn, mx)], 1);
    __syncthreads();
    for (int i = threadIdx.x; i < NTILES; i += blockDim.x)
        if (h[i]) atomicAdd(&counts[(size_t)i * CPAD], h[i]);
}

__global__ __launch_bounds__(NTILES) void scan_kernel(
    const int* __restrict__ counts, int* __restrict__ cursor)
{
    __shared__ int tmp[NTILES];
    int t = threadIdx.x;
    int my = counts[(size_t)t * CPAD];
    tmp[t] = my;
    __syncthreads();
    for (int d = 1; d < NTILES; d <<= 1) {
        int v = (t >= d) ? tmp[t - d] : 0;
        __syncthreads();
        tmp[t] += v;
        __syncthreads();
    }
    cursor[(size_t)t * CPAD] = tmp[t] - my;   // exclusive prefix -> running cursor
}

__global__ __launch_bounds__(256) void scatter_kernel(
    const float4* __restrict__ xyuv, const float* __restrict__ mn,
    const float* __restrict__ mx, int* __restrict__ cursor,
    float4* __restrict__ scoords, int* __restrict__ sidx, int npts)
{
    int stride = gridDim.x * blockDim.x;
    for (int n = blockIdx.x * blockDim.x + threadIdx.x; n < npts; n += stride) {
        float4 c = xyuv[n];
        int t = tile_of(c, mn, mx);
        int pos = atomicAdd(&cursor[(size_t)t * CPAD], 1);
        scoords[pos] = c;
        sidx[pos] = n;
    }
}

__global__ __launch_bounds__(256) void gather_kernel(
    const float4* __restrict__ scoords, const int* __restrict__ sidx,
    const float*  __restrict__ grid, const float* __restrict__ mn,
    const float*  __restrict__ mx, float* __restrict__ out, int npts)
{
    // XCD-affine bijective remap (m204 form): physical block p -> XCD p%8;
    // logical work l walks the tile-sorted point range in contiguous
    // per-XCD chunks, so each tile's grid slab lives in ONE L2.
    int nblocks = gridDim.x;
    int p   = blockIdx.x;
    int xcd = p & 7;
    int ii  = p >> 3;
    int q   = nblocks >> 3, rm = nblocks & 7;
    int l   = (xcd < rm ? xcd * (q + 1) : rm * (q + 1) + (xcd - rm) * q) + ii;

    int tid = l * blockDim.x + threadIdx.x;
    int i = tid >> 3;
    int r = tid & 7;
    if (i >= npts) return;

    float4 c = scoords[i];
    int n = sidx[i];

    float px = (c.x - mn[0]) / (mx[0] - mn[0]) * (float)(SX - 1);
    float py = (c.y - mn[1]) / (mx[1] - mn[1]) * (float)(SY - 1);
    float pu = (c.z - mn[2]) / (mx[2] - mn[2]) * (float)(SU - 1);
    float pv = (c.w - mn[3]) / (mx[3] - mn[3]) * (float)(SV - 1);

    int x0, y0, u0, v0;
    float fx, fy, fu, fv;
    split_coord(px, SX, x0, fx);
    split_coord(py, SY, y0, fy);
    split_coord(pu, SU, u0, fu);
    split_coord(pv, SV, v0, fv);

    float wx0 = 1.0f - fx, wx1 = fx;
    float wy0 = 1.0f - fy, wy1 = fy;
    float wu0 = 1.0f - fu, wu1 = fu;
    float wv0 = 1.0f - fv, wv1 = fv;

    const float* gr = grid + (size_t)r * (SX * SY * SU * SV);
    size_t buv = (size_t)u0 * SV + (size_t)v0;

    float acc = 0.0f;
#pragma unroll
    for (int dx = 0; dx < 2; ++dx) {
#pragma unroll
        for (int dy = 0; dy < 2; ++dy) {
            const float* g = gr + ((size_t)(x0 + dx) * SY + (size_t)(y0 + dy)) * (SU * SV) + buv;
            float a00 = g[0];
            float a01 = g[1];
            float a10 = g[SV];
            float a11 = g[SV + 1];
            float bu0 = a00 * wv0 + a01 * wv1;
            float bu1 = a10 * wv0 + a11 * wv1;
            float bil = bu0 * wu0 + bu1 * wu1;
            float wxy = (dx ? wx1 : wx0) * (dy ? wy1 : wy0);
            acc = fmaf(bil, wxy, acc);
        }
    }

    out[(size_t)n * RR + r] = acc;
}

// Unsorted fallback (R1 baseline) if ws is too small.
__global__ __launch_bounds__(256) void grid4d_baseline(
    const float4* __restrict__ xyuv, const float* __restrict__ grid,
    const float* __restrict__ mn, const float* __restrict__ mx,
    float* __restrict__ out, int npts)
{
    int tid = blockIdx.x * blockDim.x + threadIdx.x;
    int n = tid >> 3;
    int r = tid & 7;
    if (n >= npts) return;
    float4 c = xyuv[n];
    float px = (c.x - mn[0]) / (mx[0] - mn[0]) * (float)(SX - 1);
    float py = (c.y - mn[1]) / (mx[1] - mn[1]) * (float)(SY - 1);
    float pu = (c.z - mn[2]) / (mx[2] - mn[2]) * (float)(SU - 1);
    float pv = (c.w - mn[3]) / (mx[3] - mn[3]) * (float)(SV - 1);
    int x0, y0, u0, v0; float fx, fy, fu, fv;
    split_coord(px, SX, x0, fx); split_coord(py, SY, y0, fy);
    split_coord(pu, SU, u0, fu); split_coord(pv, SV, v0, fv);
    float wx0 = 1.0f - fx, wx1 = fx, wy0 = 1.0f - fy, wy1 = fy;
    float wu0 = 1.0f - fu, wu1 = fu, wv0 = 1.0f - fv, wv1 = fv;
    const float* gr = grid + (size_t)r * (SX * SY * SU * SV);
    size_t buv = (size_t)u0 * SV + (size_t)v0;
    float acc = 0.0f;
#pragma unroll
    for (int dx = 0; dx < 2; ++dx)
#pragma unroll
        for (int dy = 0; dy < 2; ++dy) {
            const float* g = gr + ((size_t)(x0 + dx) * SY + (size_t)(y0 + dy)) * (SU * SV) + buv;
            float bu0 = g[0] * wv0 + g[1] * wv1;
            float bu1 = g[SV] * wv0 + g[SV + 1] * wv1;
            float wxy = (dx ? wx1 : wx0) * (dy ? wy1 : wy0);
            acc = fmaf(bu0 * wu0 + bu1 * wu1, wxy, acc);
        }
    out[(size_t)n * RR + r] = acc;
}

extern "C" void kernel_launch(void* const* d_in, const int* in_sizes, int n_in,
                              void* d_out, int out_size, void* d_ws, size_t ws_size,
                              hipStream_t stream) {
    const float4* xyuv = (const float4*)d_in[0];
    const float*  grid = (const float*)d_in[1];
    const float*  mn   = (const float*)d_in[2];
    const float*  mx   = (const float*)d_in[3];
    float* out = (float*)d_out;

    int npts = in_sizes[0] / 4;

    // ws carve: counts[NTILES*CPAD] | cursor[NTILES*CPAD] | scoords[npts] (16B-aligned) | sidx[npts]
    size_t off_counts  = 0;
    size_t off_cursor  = off_counts + (size_t)NTILES * CPAD * sizeof(int);
    size_t off_scoords = (off_cursor + (size_t)NTILES * CPAD * sizeof(int) + 15) & ~(size_t)15;
    size_t off_sidx    = off_scoords + (size_t)npts * sizeof(float4);
    size_t needed      = off_sidx + (size_t)npts * sizeof(int);

    if (ws_size < needed) {
        int total = npts * RR;
        grid4d_baseline<<<(total + 255) / 256, 256, 0, stream>>>(xyuv, grid, mn, mx, out, npts);
        return;
    }

    char* ws = (char*)d_ws;
    int*    counts  = (int*)(ws + off_counts);
    int*    cursor  = (int*)(ws + off_cursor);
    float4* scoords = (float4*)(ws + off_scoords);
    int*    sidx    = (int*)(ws + off_sidx);

    zero_kernel<<<(NTILES * CPAD + 255) / 256, 256, 0, stream>>>(counts, NTILES * CPAD);
    hist_kernel<<<256, 256, 0, stream>>>(xyuv, mn, mx, counts, npts);
    scan_kernel<<<1, NTILES, 0, stream>>>(counts, cursor);
    scatter_kernel<<<1024, 256, 0, stream>>>(xyuv, mn, mx, cursor, scoords, sidx, npts);

    int total = npts * RR;
    gather_kernel<<<(total + 255) / 256, 256, 0, stream>>>(scoords, sidx, grid, mn, mx, out, npts);
}

// Round 2
// 1019.779 us; speedup vs baseline: 1.6604x; 1.2175x over previous
//
#include <hip/hip_runtime.h>

// Grid4D quadrilinear sample, align_corners=True.
// grid: [R=8, X=9, Y=9, U=512, V=512] fp32 (648 MB), xyuv: [N,4] in [0,1]
// out: [N, 8] fp32
//
// R4 (this round):
//  - gather: per-tile LDS slab staging. 8x16 (u,v) tiles -> slab = 81 planes
//    x 9x17 f32 = 49.6 KB (3 blocks/CU). Staged with global_load_lds in dense
//    17-float rows; per-point interpolation reads hit LDS (ds_read2 pairs).
//    Replaces the per-lane-unique-line gather that was L1-transaction bound
//    (R1: 462 us at 11% HBM BW, 7.6% VALU).
//  - sort: fully deterministic counting sort, ZERO global atomics:
//    hist2d[bin][blk] -> per-bin cross-block scan -> bin-offset scan ->
//    scatter with pos = binoff + blockbase + LDS-local rank. Removes the
//    device-scope returning-atomic serialization (~1000 serial RMW/counter).

#define RR 8
#define SX 9
#define SY 9
#define SU 512
#define SV 512

#define UTB 3                   // u-tile = 8
#define VTB 4                   // v-tile = 16
#define NTU (SU >> UTB)         // 64
#define NTV (SV >> VTB)         // 32
#define NTILES (NTU * NTV)      // 2048
#define NSB 256                 // scatter/hist blocks

#define PLANES (SX * SY)        // 81
#define TSU ((1 << UTB) + 1)    // 9  (u halo)
#define TSV ((1 << VTB) + 1)    // 17 (v halo)
#define PW (TSU * TSV)          // 153 words per plane
#define SLABW (PLANES * PW)     // 12393 words
#define SLABP 12544             // padded to 49*256
#define STAGE_IT (SLABP / 256)  // 49
#define PTS_CAP 3               // points per thread in gather (cnt <= 768 fast path)

__device__ __forceinline__ void split_coord(float p, int size, int& i0, float& f) {
    p = fminf(fmaxf(p, 0.0f), (float)(size - 1));
    float fl = floorf(p);
    int i = (int)fl;
    if (i > size - 2) i = size - 2;   // keep i0+1 in bounds; f hits 1.0 at top edge
    i0 = i;
    f = p - (float)i;
}

__device__ __forceinline__ int tile_of(float4 c, const float* mn, const float* mx) {
    float pu = (c.z - mn[2]) / (mx[2] - mn[2]) * (float)(SU - 1);
    float pv = (c.w - mn[3]) / (mx[3] - mn[3]) * (float)(SV - 1);
    int u0, v0; float fu, fv;
    split_coord(pu, SU, u0, fu);
    split_coord(pv, SV, v0, fv);
    return (u0 >> UTB) * NTV + (v0 >> VTB);
}

// K1: per-block histogram -> hist2d[bin*NSB + blk]
__global__ __launch_bounds__(256) void hist2d_kernel(
    const float4* __restrict__ xyuv, const float* __restrict__ mn,
    const float* __restrict__ mx, int* __restrict__ hist2d, int npts)
{
    __shared__ int h[NTILES];
    for (int i = threadIdx.x; i < NTILES; i += 256) h[i] = 0;
    __syncthreads();
    int blk = blockIdx.x;
    int ch = (npts + NSB - 1) / NSB;
    int s = blk * ch, e = min(npts, s + ch);
    for (int j = s + threadIdx.x; j < e; j += 256)
        atomicAdd(&h[tile_of(xyuv[j], mn, mx)], 1);
    __syncthreads();
    for (int i = threadIdx.x; i < NTILES; i += 256)
        hist2d[i * NSB + blk] = h[i];
}

// K2: per-bin exclusive scan across blocks (in place), bin totals out.
__global__ __launch_bounds__(NSB) void binscan_kernel(
    int* __restrict__ hist2d, int* __restrict__ bintot)
{
    __shared__ int tmp[NSB];
    int bin = blockIdx.x, t = threadIdx.x;
    int v = hist2d[bin * NSB + t];
    tmp[t] = v;
    __syncthreads();
    for (int d = 1; d < NSB; d <<= 1) {
        int o = (t >= d) ? tmp[t - d] : 0;
        __syncthreads();
        tmp[t] += o;
        __syncthreads();
    }
    hist2d[bin * NSB + t] = tmp[t] - v;       // exclusive prefix within bin
    if (t == NSB - 1) bintot[bin] = tmp[t];
}

// K3: exclusive scan of 2048 bin totals -> binoff. 1024 threads, 2 bins each.
__global__ __launch_bounds__(1024) void offscan_kernel(
    const int* __restrict__ bintot, int* __restrict__ binoff)
{
    __shared__ int tmp[1024];
    int t = threadIdx.x;
    int a = bintot[2 * t], b = bintot[2 * t + 1];
    int s = a + b;
    tmp[t] = s;
    __syncthreads();
    for (int d = 1; d < 1024; d <<= 1) {
        int o = (t >= d) ? tmp[t - d] : 0;
        __syncthreads();
        tmp[t] += o;
        __syncthreads();
    }
    int excl = tmp[t] - s;
    binoff[2 * t] = excl;
    binoff[2 * t + 1] = excl + a;
}

// K4: deterministic scatter. pos = binoff[t] + blockbase[t][blk] + local rank.
__global__ __launch_bounds__(256) void scatter2_kernel(
    const float4* __restrict__ xyuv, const float* __restrict__ mn,
    const float* __restrict__ mx, const int* __restrict__ hist2d,
    const int* __restrict__ binoff, float4* __restrict__ scoords,
    int* __restrict__ sidx, int npts)
{
    __shared__ int lh[NTILES];
    __shared__ int base2[NTILES];
    int blk = blockIdx.x, tid = threadIdx.x;
    for (int i = tid; i < NTILES; i += 256) {
        lh[i] = 0;
        base2[i] = binoff[i] + hist2d[i * NSB + blk];
    }
    __syncthreads();
    int ch = (npts + NSB - 1) / NSB;
    int s = blk * ch, e = min(npts, s + ch);
    for (int j = s + tid; j < e; j += 256) {
        float4 c = xyuv[j];
        int t = tile_of(c, mn, mx);
        int pos = base2[t] + atomicAdd(&lh[t], 1);   // LDS atomic only
        scoords[pos] = c;
        sidx[pos] = j;
    }
}

// K5: per-tile gather with LDS slab staging.
__global__ __launch_bounds__(256, 3) void gather_tiles(
    const float4* __restrict__ scoords, const int* __restrict__ sidx,
    const float* __restrict__ grid, const float* __restrict__ mn,
    const float* __restrict__ mx, const int* __restrict__ binoff,
    const int* __restrict__ bintot, float* __restrict__ out)
{
    __shared__ float slab[SLABP];

    // XCD-affine bijective remap: 2048 blocks = 8 * 256 exactly.
    int p = blockIdx.x;
    int t = (p & 7) * (NTILES / 8) + (p >> 3);
    int ut = t >> 5;            // / NTV
    int vt = t & (NTV - 1);
    int u0b = ut << UTB, v0b = vt << VTB;
    int off = binoff[t], cnt = bintot[t];
    int tid = threadIdx.x;

    // staging walker initial state for element s = tid of the slab
    int dv0 = tid % TSV;
    int rw0 = tid / TSV;
    int du0 = rw0 % TSU;
    int pp0 = rw0 / TSU;

    // per-point setup (weights computed once, reused for all 8 r)
    float wu0[PTS_CAP], wu1[PTS_CAP], wv0[PTS_CAP], wv1[PTS_CAP];
    float wxy00[PTS_CAP], wxy01[PTS_CAP], wxy10[PTS_CAP], wxy11[PTS_CAP];
    int bofs[PTS_CAP], nn[PTS_CAP];
    bool valid[PTS_CAP];
    float acc[PTS_CAP][RR];

#pragma unroll
    for (int k = 0; k < PTS_CAP; ++k) {
        int i = tid + k * 256;
        valid[k] = (i < cnt);
        int ii = valid[k] ? (off + i) : off;
        float4 c = scoords[ii];
        int n = sidx[ii];
        float px = (c.x - mn[0]) / (mx[0] - mn[0]) * (float)(SX - 1);
        float py = (c.y - mn[1]) / (mx[1] - mn[1]) * (float)(SY - 1);
        float pu = (c.z - mn[2]) / (mx[2] - mn[2]) * (float)(SU - 1);
        float pv = (c.w - mn[3]) / (mx[3] - mn[3]) * (float)(SV - 1);
        int x0, y0, u0, v0; float fx, fy, fu, fv;
        split_coord(px, SX, x0, fx);
        split_coord(py, SY, y0, fy);
        split_coord(pu, SU, u0, fu);
        split_coord(pv, SV, v0, fv);
        wu0[k] = 1.0f - fu; wu1[k] = fu;
        wv0[k] = 1.0f - fv; wv1[k] = fv;
        float wx0 = 1.0f - fx, wx1 = fx, wy0 = 1.0f - fy, wy1 = fy;
        wxy00[k] = wx0 * wy0; wxy01[k] = wx0 * wy1;
        wxy10[k] = wx1 * wy0; wxy11[k] = wx1 * wy1;
        if (!valid[k]) {
            wxy00[k] = wxy01[k] = wxy10[k] = wxy11[k] = 0.0f;
            bofs[k] = 0;
        } else {
            bofs[k] = (x0 * SY + y0) * PW + (u0 - u0b) * TSV + (v0 - v0b);
        }
        nn[k] = n;
#pragma unroll
        for (int r = 0; r < RR; ++r) acc[k][r] = 0.0f;
    }

#pragma unroll
    for (int r = 0; r < RR; ++r) {
        __syncthreads();                       // prior compute done before overwrite
        {   // stage slab for this r: dense rows of 17 floats via global_load_lds
            int dv = dv0, du = du0, pp = pp0;
            const float* gbase = grid + (size_t)(r * PLANES) * (SU * SV);
            for (int it = 0; it < STAGE_IT; ++it) {
                int pc = (pp > PLANES - 1) ? (PLANES - 1) : pp;   // pad-tail clamp
                int u = u0b + du; if (u > SU - 1) u = SU - 1;
                int v = v0b + dv; if (v > SV - 1) v = SV - 1;
                const float* src = gbase + ((size_t)pc << 18) + (u << 9) + v;
                __builtin_amdgcn_global_load_lds(
                    (const __attribute__((address_space(1))) void*)src,
                    (__attribute__((address_space(3))) void*)&slab[it * 256 + (tid & ~63u)],
                    4, 0, 0);
                // advance element index by 256 = 15*17 + 1
                dv += 1; int rowadd = 15;
                if (dv >= TSV) { dv -= TSV; rowadd = 16; }
                du += rowadd;
                if (du >= 2 * TSU) { du -= 2 * TSU; pp += 2; }
                else if (du >= TSU) { du -= TSU; pp += 1; }
            }
        }
        asm volatile("s_waitcnt vmcnt(0)" ::: "memory");
        __syncthreads();
        // compute: 16 LDS reads per (point, r)
#pragma unroll
        for (int k = 0; k < PTS_CAP; ++k) {
            int b = bofs[k];
            float a;
            {   // plane (x0, y0)
                float q00 = slab[b], q01 = slab[b + 1];
                float q10 = slab[b + TSV], q11 = slab[b + TSV + 1];
                float h0 = q00 * wv0[k] + q01 * wv1[k];
                float h1 = q10 * wv0[k] + q11 * wv1[k];
                a = (h0 * wu0[k] + h1 * wu1[k]) * wxy00[k];
            }
            {   // plane (x0, y0+1)
                int b1 = b + PW;
                float q00 = slab[b1], q01 = slab[b1 + 1];
                float q10 = slab[b1 + TSV], q11 = slab[b1 + TSV + 1];
                float h0 = q00 * wv0[k] + q01 * wv1[k];
                float h1 = q10 * wv0[k] + q11 * wv1[k];
                a = fmaf(h0 * wu0[k] + h1 * wu1[k], wxy01[k], a);
            }
            {   // plane (x0+1, y0)
                int b1 = b + SY * PW;
                float q00 = slab[b1], q01 = slab[b1 + 1];
                float q10 = slab[b1 + TSV], q11 = slab[b1 + TSV + 1];
                float h0 = q00 * wv0[k] + q01 * wv1[k];
                float h1 = q10 * wv0[k] + q11 * wv1[k];
                a = fmaf(h0 * wu0[k] + h1 * wu1[k], wxy10[k], a);
            }
            {   // plane (x0+1, y0+1)
                int b1 = b + SY * PW + PW;
                float q00 = slab[b1], q01 = slab[b1 + 1];
                float q10 = slab[b1 + TSV], q11 = slab[b1 + TSV + 1];
                float h0 = q00 * wv0[k] + q01 * wv1[k];
                float h1 = q10 * wv0[k] + q11 * wv1[k];
                a = fmaf(h0 * wu0[k] + h1 * wu1[k], wxy11[k], a);
            }
            acc[k][r] += a;
        }
    }

#pragma unroll
    for (int k = 0; k < PTS_CAP; ++k) {
        if (valid[k]) {
            float4* o = (float4*)(out + (size_t)nn[k] * RR);
            o[0] = make_float4(acc[k][0], acc[k][1], acc[k][2], acc[k][3]);
            o[1] = make_float4(acc[k][4], acc[k][5], acc[k][6], acc[k][7]);
        }
    }

    // safety net: cnt > PTS_CAP*256 (never for this input) -> direct path
    for (int i = PTS_CAP * 256 + tid; i < cnt; i += 256) {
        float4 c = scoords[off + i];
        int n = sidx[off + i];
        float px = (c.x - mn[0]) / (mx[0] - mn[0]) * (float)(SX - 1);
        float py = (c.y - mn[1]) / (mx[1] - mn[1]) * (float)(SY - 1);
        float pu = (c.z - mn[2]) / (mx[2] - mn[2]) * (float)(SU - 1);
        float pv = (c.w - mn[3]) / (mx[3] - mn[3]) * (float)(SV - 1);
        int x0, y0, u0, v0; float fx, fy, fu, fv;
        split_coord(px, SX, x0, fx); split_coord(py, SY, y0, fy);
        split_coord(pu, SU, u0, fu); split_coord(pv, SV, v0, fv);
        float wxa = 1.0f - fx, wxb = fx, wya = 1.0f - fy, wyb = fy;
        float wua = 1.0f - fu, wub = fu, wva = 1.0f - fv, wvb = fv;
        for (int r = 0; r < RR; ++r) {
            const float* gr = grid + (size_t)r * (SX * SY * SU * SV);
            size_t buv = (size_t)u0 * SV + (size_t)v0;
            float a = 0.0f;
            for (int dx = 0; dx < 2; ++dx)
                for (int dy = 0; dy < 2; ++dy) {
                    const float* g = gr + ((size_t)(x0 + dx) * SY + (size_t)(y0 + dy)) * (SU * SV) + buv;
                    float h0 = g[0] * wva + g[1] * wvb;
                    float h1 = g[SV] * wva + g[SV + 1] * wvb;
                    float wxy = (dx ? wxb : wxa) * (dy ? wyb : wya);
                    a = fmaf(h0 * wua + h1 * wub, wxy, a);
                }
            out[(size_t)n * RR + r] = a;
        }
    }
}

// Unsorted fallback if ws is too small.
__global__ __launch_bounds__(256) void grid4d_baseline(
    const float4* __restrict__ xyuv, const float* __restrict__ grid,
    const float* __restrict__ mn, const float* __restrict__ mx,
    float* __restrict__ out, int npts)
{
    int tid = blockIdx.x * blockDim.x + threadIdx.x;
    int n = tid >> 3;
    int r = tid & 7;
    if (n >= npts) return;
    float4 c = xyuv[n];
    float px = (c.x - mn[0]) / (mx[0] - mn[0]) * (float)(SX - 1);
    float py = (c.y - mn[1]) / (mx[1] - mn[1]) * (float)(SY - 1);
    float pu = (c.z - mn[2]) / (mx[2] - mn[2]) * (float)(SU - 1);
    float pv = (c.w - mn[3]) / (mx[3] - mn[3]) * (float)(SV - 1);
    int x0, y0, u0, v0; float fx, fy, fu, fv;
    split_coord(px, SX, x0, fx); split_coord(py, SY, y0, fy);
    split_coord(pu, SU, u0, fu); split_coord(pv, SV, v0, fv);
    float wx0 = 1.0f - fx, wx1 = fx, wy0 = 1.0f - fy, wy1 = fy;
    float wu0 = 1.0f - fu, wu1 = fu, wv0 = 1.0f - fv, wv1 = fv;
    const float* gr = grid + (size_t)r * (SX * SY * SU * SV);
    size_t buv = (size_t)u0 * SV + (size_t)v0;
    float acc = 0.0f;
#pragma unroll
    for (int dx = 0; dx < 2; ++dx)
#pragma unroll
        for (int dy = 0; dy < 2; ++dy) {
            const float* g = gr + ((size_t)(x0 + dx) * SY + (size_t)(y0 + dy)) * (SU * SV) + buv;
            float bu0 = g[0] * wv0 + g[1] * wv1;
            float bu1 = g[SV] * wv0 + g[SV + 1] * wv1;
            float wxy = (dx ? wx1 : wx0) * (dy ? wy1 : wy0);
            acc = fmaf(bu0 * wu0 + bu1 * wu1, wxy, acc);
        }
    out[(size_t)n * RR + r] = acc;
}

extern "C" void kernel_launch(void* const* d_in, const int* in_sizes, int n_in,
                              void* d_out, int out_size, void* d_ws, size_t ws_size,
                              hipStream_t stream) {
    const float4* xyuv = (const float4*)d_in[0];
    const float*  grid = (const float*)d_in[1];
    const float*  mn   = (const float*)d_in[2];
    const float*  mx   = (const float*)d_in[3];
    float* out = (float*)d_out;

    int npts = in_sizes[0] / 4;

    // ws carve: hist2d[NTILES*NSB] | bintot[NTILES] | binoff[NTILES] |
    //           scoords[npts] (16B-aligned) | sidx[npts]
    size_t off_h2 = 0;
    size_t off_bt = off_h2 + (size_t)NTILES * NSB * sizeof(int);
    size_t off_bo = off_bt + (size_t)NTILES * sizeof(int);
    size_t off_sc = (off_bo + (size_t)NTILES * sizeof(int) + 15) & ~(size_t)15;
    size_t off_si = off_sc + (size_t)npts * sizeof(float4);
    size_t needed = off_si + (size_t)npts * sizeof(int);

    if (ws_size < needed) {
        int total = npts * RR;
        grid4d_baseline<<<(total + 255) / 256, 256, 0, stream>>>(xyuv, grid, mn, mx, out, npts);
        return;
    }

    char* ws = (char*)d_ws;
    int*    hist2d  = (int*)(ws + off_h2);
    int*    bintot  = (int*)(ws + off_bt);
    int*    binoff  = (int*)(ws + off_bo);
    float4* scoords = (float4*)(ws + off_sc);
    int*    sidx    = (int*)(ws + off_si);

    hist2d_kernel <<<NSB, 256, 0, stream>>>(xyuv, mn, mx, hist2d, npts);
    binscan_kernel<<<NTILES, NSB, 0, stream>>>(hist2d, bintot);
    offscan_kernel<<<1, 1024, 0, stream>>>(bintot, binoff);
    scatter2_kernel<<<NSB, 256, 0, stream>>>(xyuv, mn, mx, hist2d, binoff, scoords, sidx, npts);
    gather_tiles  <<<NTILES, 256, 0, stream>>>(scoords, sidx, grid, mn, mx, binoff, bintot, out);
}